// Round 12
// baseline (118.187 us; speedup 1.0000x reference)
//
#include <hip/hip_runtime.h>

typedef __attribute__((ext_vector_type(8))) short bf16x8;
typedef __attribute__((ext_vector_type(16))) float f32x16;
typedef __attribute__((ext_vector_type(4))) float f32x4;

__device__ inline unsigned short f2bf_rne(float x) {
  unsigned u = __float_as_uint(x);
  unsigned r = u + 0x7FFFu + ((u >> 16) & 1u);
  return (unsigned short)(r >> 16);
}
__device__ inline float bf2f(unsigned short h) {
  return __uint_as_float(((unsigned)h) << 16);
}

// ---------- P0 fused: encpk (blocks 0..9215) + mprep (blocks 9216..9983) ----------
__global__ __launch_bounds__(256) void pre_kernel(const float* __restrict__ enc,
                                                  unsigned* __restrict__ encpk,
                                                  const int* __restrict__ mask,
                                                  float* __restrict__ mprep) {
  int bid = blockIdx.x;
  if (bid < 9216) {
    int h = bid * 256 + threadIdx.x;            // < 2359296
    f32x4 v = *(const f32x4*)(enc + (size_t)h * 4);
    unsigned lo = (unsigned)f2bf_rne(v[0]) | ((unsigned)f2bf_rne(v[1]) << 16);
    unsigned hi = (unsigned)f2bf_rne(v[2]) | ((unsigned)f2bf_rne(v[3]) << 16);
    uint2 o; o.x = lo; o.y = hi;
    *(uint2*)(encpk + (size_t)h * 2) = o;
  } else {
    int i = bid - 9216, t = threadIdx.x;
    int sum = 0;
    for (int j = t; j < 768; j += 256) sum += mask[i*768 + j];
    for (int off = 32; off; off >>= 1) sum += __shfl_down(sum, off, 64);
    __shared__ int part[4];
    __shared__ float inv_s;
    if ((t & 63) == 0) part[t >> 6] = sum;
    __syncthreads();
    if (t == 0) inv_s = 1.0f / (float)(part[0] + part[1] + part[2] + part[3]);
    __syncthreads();
    float inv = inv_s;
    for (int j = t; j < 768; j += 256) mprep[i*768 + j] = (float)mask[i*768 + j] * inv;
  }
}

// ---------- P1: per-node A (hi/lo bf16, b-interleaved) + Zej (fp32); 16 nodes/block ----------
// block 0 packs wpk/w2pad; block 1 zeroes sacc (runs before edge in-stream).
__global__ __launch_bounds__(256) void prep_kernel(const float* __restrict__ seq,
                                                   const float* __restrict__ W1,
                                                   const float* __restrict__ b1,
                                                   const float* __restrict__ W2,
                                                   unsigned* __restrict__ apk2,
                                                   float* __restrict__ zej,
                                                   unsigned* __restrict__ wpk,
                                                   float* __restrict__ w2pad,
                                                   float* __restrict__ sacc) {
  const int bi0 = blockIdx.x * 16;
  __shared__ float sq[16][64];
  for (int q = threadIdx.x; q < 16*64; q += 256)
    sq[q >> 6][q & 63] = seq[bi0*64 + q];
  __syncthreads();
  const int c = threadIdx.x;
  if (c < 144) {
    float accA[16], accZ[16];
#pragma unroll
    for (int n = 0; n < 16; ++n) { accA[n] = b1[c]; accZ[n] = 0.f; }
#pragma unroll 4
    for (int u = 0; u < 64; ++u) {
      float wa = W1[u*144 + c];
      float wz = W1[(64 + u)*144 + c];
#pragma unroll
      for (int n = 0; n < 16; ++n) {
        float s = sq[n][u];
        accA[n] = fmaf(s, wa, accA[n]);
        accZ[n] = fmaf(s, wz, accZ[n]);
      }
    }
#pragma unroll
    for (int n = 0; n < 16; ++n) {
      int bi = bi0 + n;
      int b = (bi >= 768) ? 1 : 0;
      int nr = bi - b*768;
      unsigned short hi = f2bf_rne(accA[n]);
      unsigned short lo = f2bf_rne(accA[n] - bf2f(hi));
      apk2[(nr*160 + c)*2 + b] = (unsigned)hi | ((unsigned)lo << 16);
      zej[bi*160 + c] = accZ[n];
    }
  } else if (c < 160) {
#pragma unroll
    for (int n = 0; n < 16; ++n) {
      int bi = bi0 + n;
      int b = (bi >= 768) ? 1 : 0;
      int nr = bi - b*768;
      apk2[(nr*160 + c)*2 + b] = 0u;
      zej[bi*160 + c] = 0.f;
    }
  }
  if (blockIdx.x == 0) {
    for (int g = threadIdx.x; g < 1440; g += 256) {
      if (g < 1280) {
        int ew = g & 3;
        int l = (g >> 2) & 63;
        int t = g >> 8;                 // c-tile 0..4
        int cc = t*32 + (l & 31);
        unsigned short h[2];
#pragma unroll
        for (int q = 0; q < 2; ++q) {
          int e = ew*2 + q;
          int koff = (l >> 5)*8 + e;    // k-channel 0..15
          float v = (cc < 144) ? W1[(128 + koff)*144 + cc] : 0.f;
          h[q] = f2bf_rne(v);
        }
        wpk[g] = (unsigned)h[0] | ((unsigned)h[1] << 16);
      } else {
        int cc = g - 1280;
        w2pad[cc] = (cc < 144) ? W2[cc] : 0.f;
      }
    }
  } else if (blockIdx.x == 1) {
    for (int g = threadIdx.x; g < 1536; g += 256) sacc[g] = 0.f;
  }
}

// ---------- edge kernel: XCD-chunked swizzle + per-wave 6-slot DMA rings ----------
// All 768 blocks co-resident (3/CU). Swizzle puts the 24 same-y-stripe blocks
// (identical enc rows) on one XCD so its 4MB L2 holds the stripe working set
// (~1.4MB) -> enc/apk loads are L2 hits, covered by distance-4 prefetch.
__global__ __launch_bounds__(320, 3) void edge_kernel(
    const unsigned* __restrict__ encpk, const uint2* __restrict__ apkp,
    const float* __restrict__ zej, const unsigned* __restrict__ wpk,
    const float* __restrict__ w2pad, const float* __restrict__ b2p,
    const float* __restrict__ mprep, float* __restrict__ s_out) {
  const int tid = threadIdx.x;
  const int lane = tid & 63;
  const int w = tid >> 6;          // c-tile 0..4
  // physical round-robin p%8 -> XCD k gets contiguous work chunk [k*96,(k+1)*96)
  const int p = blockIdx.x;        // 0..767
  const int work = (p & 7) * 96 + (p >> 3);
  const int jb = work % 24;
  const int i0 = (work / 24) * 24; // y-stripe * 24
  const int l31 = lane & 31, lh = lane >> 5;
  const int jglob = jb*32 + l31;

  bf16x8 wfrag = ((const bf16x8*)wpk)[w*64 + lane];

  float w2own[16];
#pragma unroll
  for (int r = 0; r < 16; ++r)
    w2own[r] = w2pad[w*32 + (r & 3) + 8*(r >> 2) + 4*lh];

  // Zej C-inits (fp32, C/D layout), one per batch
  f32x16 Cz0, Cz1;
#pragma unroll
  for (int q = 0; q < 4; ++q) {
    f32x4 z0 = *(const f32x4*)&zej[(0*768 + jglob)*160 + w*32 + 4*lh + 8*q];
    f32x4 z1 = *(const f32x4*)&zej[(768   + jglob)*160 + w*32 + 4*lh + 8*q];
#pragma unroll
    for (int m = 0; m < 4; ++m) { Cz0[q*4 + m] = z0[m]; Cz1[q*4 + m] = z1[m]; }
  }

  // mprep preload (reduction phase then touches no global memory)
  float mp[4][2];
  if (tid < 192) {
    const int j = tid & 31, g6 = tid >> 5;
#pragma unroll
    for (int s = 0; s < 4; ++s) {
      int i1 = i0 + s*6 + (g6 >> 1);
      mp[s][0] = mprep[i1*768 + jb*32 + j];
      mp[s][1] = mprep[(i1 + 3)*768 + jb*32 + j];
    }
  } else {
#pragma unroll
    for (int s = 0; s < 4; ++s) { mp[s][0] = 0.f; mp[s][1] = 0.f; }
  }

  bf16x8 ones;
#pragma unroll
  for (int e = 0; e < 8; ++e) ones[e] = 0;
  if (lh == 0) { ones[0] = (short)0x3F80; ones[1] = (short)0x3F80; }

  __shared__ float pdot[5][2][12][32];               // 15 KB (one 6-i segment)
  __shared__ float scomb[192];                       // 0.75 KB
  __shared__ __align__(16) char lds_enc[5][6][1024]; // 30 KB per-wave rings
  const float b2 = *b2p;

  // drain prologue vmem so steady-state vmcnt counts are exact
  asm volatile("s_waitcnt vmcnt(0)" ::: "memory");
  __builtin_amdgcn_sched_barrier(0);

  uint2 apkv[6];

#define GLD_ENC(I, SLOT)                                                        \
  __builtin_amdgcn_global_load_lds(                                            \
      (const __attribute__((address_space(1))) unsigned*)(encpk +              \
          (size_t)(i0 + (I))*6144 + jb*256 + l31*8 + lh*4),                     \
      (__attribute__((address_space(3))) unsigned*)&lds_enc[w][SLOT][0], 16, 0, 0)
#define APK(I, SLOT) apkv[SLOT] = apkp[(i0 + (I))*160 + w*32 + l31]

  // prologue: pairs 0..3 in flight (8 vmem ops), prefetch distance 4
  GLD_ENC(0, 0); APK(0, 0);
  GLD_ENC(1, 1); APK(1, 1);
  GLD_ENC(2, 2); APK(2, 2);
  GLD_ENC(3, 3); APK(3, 3);

  float sacc_t = 0.f;

  auto body = [&](int unit, int slot) {
    bf16x8 encf = *(const bf16x8*)(&lds_enc[w][slot][lane*16]);
    uint2 av = apkv[slot];

    f32x16 Ce0 = __builtin_amdgcn_mfma_f32_32x32x16_bf16(wfrag, encf, Cz0, 0, 0, 0);
    f32x16 Ce1 = __builtin_amdgcn_mfma_f32_32x32x16_bf16(wfrag, encf, Cz1, 0, 0, 0);

    bf16x8 af0, af1;
#pragma unroll
    for (int e = 2; e < 8; ++e) { af0[e] = 0; af1[e] = 0; }
    *(unsigned*)&af0 = av.x;   // hi|lo bf16 pair -> elems 0,1
    *(unsigned*)&af1 = av.y;

    f32x16 Cb0 = __builtin_amdgcn_mfma_f32_32x32x16_bf16(af0, ones, Ce0, 0, 0, 0);
    f32x16 Cb1 = __builtin_amdgcn_mfma_f32_32x32x16_bf16(af1, ones, Ce1, 0, 0, 0);

    // dot with leaky via h = 0.505z + 0.495|z|  (|.| is a free input modifier)
    float ta0[2] = {0.f, 0.f}, tb0[2] = {0.f, 0.f};
    float ta1[2] = {0.f, 0.f}, tb1[2] = {0.f, 0.f};
#pragma unroll
    for (int r = 0; r < 16; ++r) {
      float z0 = Cb0[r], z1 = Cb1[r];
      ta0[r & 1] = fmaf(z0, w2own[r], ta0[r & 1]);
      tb0[r & 1] = fmaf(fabsf(z0), w2own[r], tb0[r & 1]);
      ta1[r & 1] = fmaf(z1, w2own[r], ta1[r & 1]);
      tb1[r & 1] = fmaf(fabsf(z1), w2own[r], tb1[r & 1]);
    }
    float dp0 = 0.505f*(ta0[0] + ta0[1]) + 0.495f*(tb0[0] + tb0[1]);
    float dp1 = 0.505f*(ta1[0] + ta1[1]) + 0.495f*(tb1[0] + tb1[1]);
    pdot[w][lh][unit + 0][l31] = dp0;
    pdot[w][lh][unit + 1][l31] = dp1;
  };

#define STEP(IL, VM)                                                            \
  do {                                                                          \
    if ((IL) < 20) { GLD_ENC((IL) + 4, ((IL) + 4) % 6); APK((IL) + 4, ((IL) + 4) % 6); } \
    asm volatile("s_waitcnt vmcnt(" #VM ")" ::: "memory");                      \
    __builtin_amdgcn_sched_barrier(0);                                          \
    body(((IL) % 6) * 2, (IL) % 6);                                             \
  } while (0)

#define REDUCE(S, LAST)                                                         \
  do {                                                                          \
    asm volatile("s_waitcnt lgkmcnt(0)" ::: "memory");                          \
    __builtin_amdgcn_sched_barrier(0);                                          \
    __builtin_amdgcn_s_barrier();                                               \
    if (tid < 192) {                                                            \
      const int j = tid & 31, g6 = tid >> 5;                                    \
      float s1 = 0.f, s2 = 0.f;                                                 \
      _Pragma("unroll")                                                         \
      for (int w5 = 0; w5 < 5; ++w5) {                                          \
        s1 += pdot[w5][0][g6][j] + pdot[w5][1][g6][j];                          \
        s2 += pdot[w5][0][g6 + 6][j] + pdot[w5][1][g6 + 6][j];                  \
      }                                                                         \
      float wv1 = s1 + b2; wv1 = fmaxf(wv1, 0.01f*wv1);                         \
      float wv2 = s2 + b2; wv2 = fmaxf(wv2, 0.01f*wv2);                         \
      sacc_t = fmaf(mp[S][0], wv1, sacc_t);                                     \
      sacc_t = fmaf(mp[S][1], wv2, sacc_t);                                     \
    }                                                                           \
    if (!(LAST)) {                                                              \
      asm volatile("s_waitcnt lgkmcnt(0)" ::: "memory");                        \
      __builtin_amdgcn_sched_barrier(0);                                        \
      __builtin_amdgcn_s_barrier();                                             \
    }                                                                           \
  } while (0)

  STEP(0, 8);  STEP(1, 8);  STEP(2, 8);  STEP(3, 8);  STEP(4, 8);  STEP(5, 8);
  REDUCE(0, 0);
  STEP(6, 8);  STEP(7, 8);  STEP(8, 8);  STEP(9, 8);  STEP(10, 8); STEP(11, 8);
  REDUCE(1, 0);
  STEP(12, 8); STEP(13, 8); STEP(14, 8); STEP(15, 8); STEP(16, 8); STEP(17, 8);
  REDUCE(2, 0);
  STEP(18, 8); STEP(19, 8); STEP(20, 6); STEP(21, 4); STEP(22, 2); STEP(23, 0);
  REDUCE(3, 1);
#undef STEP
#undef REDUCE
#undef GLD_ENC
#undef APK

  if (tid < 192) scomb[tid] = sacc_t;
  __syncthreads();
  if (tid < 64) {
    const int b = tid >> 5, j = tid & 31;
    float tot = scomb[b*32 + j] + scomb[(b + 2)*32 + j] + scomb[(b + 4)*32 + j];
    atomicAdd(&s_out[b*768 + jb*32 + j], tot);
  }
}

// ---------- seq' = s * seq ----------
__global__ __launch_bounds__(256) void scale_kernel(const float* __restrict__ s,
                                                    const float* __restrict__ seq_in,
                                                    float* __restrict__ seq_out) {
  int idx = blockIdx.x * 256 + threadIdx.x;
  seq_out[idx] = s[idx >> 6] * seq_in[idx];
}

extern "C" void kernel_launch(void* const* d_in, const int* in_sizes, int n_in,
                              void* d_out, int out_size, void* d_ws, size_t ws_size,
                              hipStream_t stream) {
  const float* seq  = (const float*)d_in[0];
  const float* enc  = (const float*)d_in[1];
  const int*   mask = (const int*)d_in[2];
  const float* W11  = (const float*)d_in[3];
  const float* b11  = (const float*)d_in[4];
  const float* W12  = (const float*)d_in[5];
  const float* b12  = (const float*)d_in[6];
  const float* W21  = (const float*)d_in[7];
  const float* b21  = (const float*)d_in[8];
  const float* W22  = (const float*)d_in[9];
  const float* b22  = (const float*)d_in[10];
  float* out = (float*)d_out;

  float* ws = (float*)d_ws;
  size_t off = 0;
  float* mprep = ws + off;                 off += 768*768;
  unsigned* apk2 = (unsigned*)(ws + off);  off += 2*768*160;
  float* zej = ws + off;                   off += 2*768*160;
  unsigned* wpk = (unsigned*)(ws + off);   off += 1280;
  float* w2pad = ws + off;                 off += 160;
  float* sacc  = ws + off;                 off += 2*768;
  float* seq_mid = ws + off;               off += 2*768*64;
  unsigned* encpk = (unsigned*)(ws + off); off += 768*768*8;

  pre_kernel<<<9984, 256, 0, stream>>>(enc, encpk, mask, mprep);

  // hop 1
  prep_kernel<<<96, 256, 0, stream>>>(seq, W11, b11, W12, apk2, zej, wpk, w2pad, sacc);
  edge_kernel<<<768, 320, 0, stream>>>(encpk, (const uint2*)apk2, zej, wpk,
                                       w2pad, b12, mprep, sacc);
  scale_kernel<<<384, 256, 0, stream>>>(sacc, seq, seq_mid);

  // hop 2
  prep_kernel<<<96, 256, 0, stream>>>(seq_mid, W21, b21, W22, apk2, zej, wpk, w2pad, sacc);
  edge_kernel<<<768, 320, 0, stream>>>(encpk, (const uint2*)apk2, zej, wpk,
                                       w2pad, b22, mprep, sacc);
  scale_kernel<<<384, 256, 0, stream>>>(sacc, seq_mid, out);
}

// Round 13
// 101.621 us; speedup vs baseline: 1.1630x; 1.1630x over previous
//
#include <hip/hip_runtime.h>

typedef __attribute__((ext_vector_type(8))) short bf16x8;
typedef __attribute__((ext_vector_type(16))) float f32x16;
typedef __attribute__((ext_vector_type(4))) float f32x4;

__device__ inline unsigned short f2bf_rne(float x) {
  unsigned u = __float_as_uint(x);
  unsigned r = u + 0x7FFFu + ((u >> 16) & 1u);
  return (unsigned short)(r >> 16);
}
__device__ inline float bf2f(unsigned short h) {
  return __uint_as_float(((unsigned)h) << 16);
}

// ---------- P0 fused: encpk (blocks 0..9215) + mprep (blocks 9216..9983) ----------
__global__ __launch_bounds__(256) void pre_kernel(const float* __restrict__ enc,
                                                  unsigned* __restrict__ encpk,
                                                  const int* __restrict__ mask,
                                                  float* __restrict__ mprep) {
  int bid = blockIdx.x;
  if (bid < 9216) {
    int h = bid * 256 + threadIdx.x;            // < 2359296
    f32x4 v = *(const f32x4*)(enc + (size_t)h * 4);
    unsigned lo = (unsigned)f2bf_rne(v[0]) | ((unsigned)f2bf_rne(v[1]) << 16);
    unsigned hi = (unsigned)f2bf_rne(v[2]) | ((unsigned)f2bf_rne(v[3]) << 16);
    uint2 o; o.x = lo; o.y = hi;
    *(uint2*)(encpk + (size_t)h * 2) = o;
  } else {
    int i = bid - 9216, t = threadIdx.x;
    int sum = 0;
    for (int j = t; j < 768; j += 256) sum += mask[i*768 + j];
    for (int off = 32; off; off >>= 1) sum += __shfl_down(sum, off, 64);
    __shared__ int part[4];
    __shared__ float inv_s;
    if ((t & 63) == 0) part[t >> 6] = sum;
    __syncthreads();
    if (t == 0) inv_s = 1.0f / (float)(part[0] + part[1] + part[2] + part[3]);
    __syncthreads();
    float inv = inv_s;
    for (int j = t; j < 768; j += 256) mprep[i*768 + j] = (float)mask[i*768 + j] * inv;
  }
}

// ---------- P1: per-node A (hi/lo bf16, b-interleaved) + Zej (fp32); 16 nodes/block ----------
// SCALED: applies s_in per node to seq inline (fuses the former scale_kernel) and
// writes seq_mid. block 0 packs wpk/w2pad; block 1 zeroes sacc_zero.
template<bool SCALED>
__global__ __launch_bounds__(256) void prep_kernel(const float* __restrict__ seq,
                                                   const float* __restrict__ s_in,
                                                   float* __restrict__ seq_mid,
                                                   const float* __restrict__ W1,
                                                   const float* __restrict__ b1,
                                                   const float* __restrict__ W2,
                                                   unsigned* __restrict__ apk2,
                                                   float* __restrict__ zej,
                                                   unsigned* __restrict__ wpk,
                                                   float* __restrict__ w2pad,
                                                   float* __restrict__ sacc_zero) {
  const int bi0 = blockIdx.x * 16;
  __shared__ float sq[16][64];
  for (int q = threadIdx.x; q < 16*64; q += 256) {
    float v = seq[bi0*64 + q];
    if (SCALED) {
      v *= s_in[bi0 + (q >> 6)];
      seq_mid[bi0*64 + q] = v;
    }
    sq[q >> 6][q & 63] = v;
  }
  __syncthreads();
  const int c = threadIdx.x;
  if (c < 144) {
    float accA[16], accZ[16];
#pragma unroll
    for (int n = 0; n < 16; ++n) { accA[n] = b1[c]; accZ[n] = 0.f; }
#pragma unroll 4
    for (int u = 0; u < 64; ++u) {
      float wa = W1[u*144 + c];
      float wz = W1[(64 + u)*144 + c];
#pragma unroll
      for (int n = 0; n < 16; ++n) {
        float s = sq[n][u];
        accA[n] = fmaf(s, wa, accA[n]);
        accZ[n] = fmaf(s, wz, accZ[n]);
      }
    }
#pragma unroll
    for (int n = 0; n < 16; ++n) {
      int bi = bi0 + n;
      int b = (bi >= 768) ? 1 : 0;
      int nr = bi - b*768;
      unsigned short hi = f2bf_rne(accA[n]);
      unsigned short lo = f2bf_rne(accA[n] - bf2f(hi));
      apk2[(nr*160 + c)*2 + b] = (unsigned)hi | ((unsigned)lo << 16);
      zej[bi*160 + c] = accZ[n];
    }
  } else if (c < 160) {
#pragma unroll
    for (int n = 0; n < 16; ++n) {
      int bi = bi0 + n;
      int b = (bi >= 768) ? 1 : 0;
      int nr = bi - b*768;
      apk2[(nr*160 + c)*2 + b] = 0u;
      zej[bi*160 + c] = 0.f;
    }
  }
  if (blockIdx.x == 0) {
    for (int g = threadIdx.x; g < 1440; g += 256) {
      if (g < 1280) {
        int ew = g & 3;
        int l = (g >> 2) & 63;
        int t = g >> 8;                 // c-tile 0..4
        int cc = t*32 + (l & 31);
        unsigned short h[2];
#pragma unroll
        for (int q = 0; q < 2; ++q) {
          int e = ew*2 + q;
          int koff = (l >> 5)*8 + e;    // k-channel 0..15
          float v = (cc < 144) ? W1[(128 + koff)*144 + cc] : 0.f;
          h[q] = f2bf_rne(v);
        }
        wpk[g] = (unsigned)h[0] | ((unsigned)h[1] << 16);
      } else {
        int cc = g - 1280;
        w2pad[cc] = (cc < 144) ? W2[cc] : 0.f;
      }
    }
  } else if (blockIdx.x == 1) {
    for (int g = threadIdx.x; g < 1536; g += 256) sacc_zero[g] = 0.f;
  }
}

// ---------- edge kernel: per-wave DMA rings (depth 4), scalar fabsf dot ----------
// R11-proven body. Per-step sched_barrier(0) removed: the asm "memory" clobber on
// each vmcnt already orders DMA/ds_read/loads; register-only dot FMAs may now
// float across the wait to fill the dependent-MFMA bubble of the next step.
__global__ __launch_bounds__(320, 3) void edge_kernel(
    const unsigned* __restrict__ encpk, const uint2* __restrict__ apkp,
    const float* __restrict__ zej, const unsigned* __restrict__ wpk,
    const float* __restrict__ w2pad, const float* __restrict__ b2p,
    const float* __restrict__ mprep, float* __restrict__ s_out) {
  const int tid = threadIdx.x;
  const int lane = tid & 63;
  const int w = tid >> 6;          // c-tile 0..4
  const int jb = blockIdx.x;       // 0..23
  const int i0 = blockIdx.y * 24;  // 32 i-blocks
  const int l31 = lane & 31, lh = lane >> 5;
  const int jglob = jb*32 + l31;

  bf16x8 wfrag = ((const bf16x8*)wpk)[w*64 + lane];

  float w2own[16];
#pragma unroll
  for (int r = 0; r < 16; ++r)
    w2own[r] = w2pad[w*32 + (r & 3) + 8*(r >> 2) + 4*lh];

  // Zej C-inits (fp32, C/D layout), one per batch
  f32x16 Cz0, Cz1;
#pragma unroll
  for (int q = 0; q < 4; ++q) {
    f32x4 z0 = *(const f32x4*)&zej[(0*768 + jglob)*160 + w*32 + 4*lh + 8*q];
    f32x4 z1 = *(const f32x4*)&zej[(768   + jglob)*160 + w*32 + 4*lh + 8*q];
#pragma unroll
    for (int m = 0; m < 4; ++m) { Cz0[q*4 + m] = z0[m]; Cz1[q*4 + m] = z1[m]; }
  }

  // mprep preload (reduction phase then touches no global memory)
  float mp[4][2];
  if (tid < 192) {
    const int j = tid & 31, g6 = tid >> 5;
#pragma unroll
    for (int s = 0; s < 4; ++s) {
      int i1 = i0 + s*6 + (g6 >> 1);
      mp[s][0] = mprep[i1*768 + jb*32 + j];
      mp[s][1] = mprep[(i1 + 3)*768 + jb*32 + j];
    }
  } else {
#pragma unroll
    for (int s = 0; s < 4; ++s) { mp[s][0] = 0.f; mp[s][1] = 0.f; }
  }

  bf16x8 ones;
#pragma unroll
  for (int e = 0; e < 8; ++e) ones[e] = 0;
  if (lh == 0) { ones[0] = (short)0x3F80; ones[1] = (short)0x3F80; }

  __shared__ float pdot[5][2][12][32];               // 15 KB (one 6-i segment)
  __shared__ float scomb[192];                       // 0.75 KB
  __shared__ __align__(16) char lds_enc[5][4][1024]; // 20 KB per-wave rings
  const float b2 = *b2p;

  // drain prologue vmem so steady-state vmcnt counts are exact
  asm volatile("s_waitcnt vmcnt(0)" ::: "memory");
  __builtin_amdgcn_sched_barrier(0);

  uint2 apkv[4];

#define GLD_ENC(I, SLOT)                                                        \
  __builtin_amdgcn_global_load_lds(                                            \
      (const __attribute__((address_space(1))) unsigned*)(encpk +              \
          (size_t)(i0 + (I))*6144 + jb*256 + l31*8 + lh*4),                     \
      (__attribute__((address_space(3))) unsigned*)&lds_enc[w][SLOT][0], 16, 0, 0)
#define APK(I, SLOT) apkv[SLOT] = apkp[(i0 + (I))*160 + w*32 + l31]

  // prologue: pairs 0..2 in flight (6 vmem ops), prefetch distance 3
  GLD_ENC(0, 0); APK(0, 0);
  GLD_ENC(1, 1); APK(1, 1);
  GLD_ENC(2, 2); APK(2, 2);

  float sacc_t = 0.f;

  auto body = [&](int unit, int slot) {
    bf16x8 encf = *(const bf16x8*)(&lds_enc[w][slot][lane*16]);
    uint2 av = apkv[slot];

    f32x16 Ce0 = __builtin_amdgcn_mfma_f32_32x32x16_bf16(wfrag, encf, Cz0, 0, 0, 0);
    f32x16 Ce1 = __builtin_amdgcn_mfma_f32_32x32x16_bf16(wfrag, encf, Cz1, 0, 0, 0);

    bf16x8 af0, af1;
#pragma unroll
    for (int e = 2; e < 8; ++e) { af0[e] = 0; af1[e] = 0; }
    *(unsigned*)&af0 = av.x;   // hi|lo bf16 pair -> elems 0,1
    *(unsigned*)&af1 = av.y;

    f32x16 Cb0 = __builtin_amdgcn_mfma_f32_32x32x16_bf16(af0, ones, Ce0, 0, 0, 0);
    f32x16 Cb1 = __builtin_amdgcn_mfma_f32_32x32x16_bf16(af1, ones, Ce1, 0, 0, 0);

    // dot with leaky via h = 0.505z + 0.495|z|  (|.| is a free input modifier)
    float ta0[2] = {0.f, 0.f}, tb0[2] = {0.f, 0.f};
    float ta1[2] = {0.f, 0.f}, tb1[2] = {0.f, 0.f};
#pragma unroll
    for (int r = 0; r < 16; ++r) {
      float z0 = Cb0[r], z1 = Cb1[r];
      ta0[r & 1] = fmaf(z0, w2own[r], ta0[r & 1]);
      tb0[r & 1] = fmaf(fabsf(z0), w2own[r], tb0[r & 1]);
      ta1[r & 1] = fmaf(z1, w2own[r], ta1[r & 1]);
      tb1[r & 1] = fmaf(fabsf(z1), w2own[r], tb1[r & 1]);
    }
    float dp0 = 0.505f*(ta0[0] + ta0[1]) + 0.495f*(tb0[0] + tb0[1]);
    float dp1 = 0.505f*(ta1[0] + ta1[1]) + 0.495f*(tb1[0] + tb1[1]);
    pdot[w][lh][unit + 0][l31] = dp0;
    pdot[w][lh][unit + 1][l31] = dp1;
  };

#define STEP(IL, VM)                                                            \
  do {                                                                          \
    if ((IL) < 21) { GLD_ENC((IL) + 3, ((IL) + 3) & 3); APK((IL) + 3, ((IL) + 3) & 3); } \
    asm volatile("s_waitcnt vmcnt(" #VM ")" ::: "memory");                      \
    body(((IL) % 6) * 2, (IL) & 3);                                             \
  } while (0)

#define REDUCE(S, LAST)                                                         \
  do {                                                                          \
    asm volatile("s_waitcnt lgkmcnt(0)" ::: "memory");                          \
    __builtin_amdgcn_sched_barrier(0);                                          \
    __builtin_amdgcn_s_barrier();                                               \
    if (tid < 192) {                                                            \
      const int j = tid & 31, g6 = tid >> 5;                                    \
      float s1 = 0.f, s2 = 0.f;                                                 \
      _Pragma("unroll")                                                         \
      for (int w5 = 0; w5 < 5; ++w5) {                                          \
        s1 += pdot[w5][0][g6][j] + pdot[w5][1][g6][j];                          \
        s2 += pdot[w5][0][g6 + 6][j] + pdot[w5][1][g6 + 6][j];                  \
      }                                                                         \
      float wv1 = s1 + b2; wv1 = fmaxf(wv1, 0.01f*wv1);                         \
      float wv2 = s2 + b2; wv2 = fmaxf(wv2, 0.01f*wv2);                         \
      sacc_t = fmaf(mp[S][0], wv1, sacc_t);                                     \
      sacc_t = fmaf(mp[S][1], wv2, sacc_t);                                     \
    }                                                                           \
    if (!(LAST)) {                                                              \
      asm volatile("s_waitcnt lgkmcnt(0)" ::: "memory");                        \
      __builtin_amdgcn_sched_barrier(0);                                        \
      __builtin_amdgcn_s_barrier();                                             \
    }                                                                           \
  } while (0)

  STEP(0, 6);  STEP(1, 6);  STEP(2, 6);  STEP(3, 6);  STEP(4, 6);  STEP(5, 6);
  REDUCE(0, 0);
  STEP(6, 6);  STEP(7, 6);  STEP(8, 6);  STEP(9, 6);  STEP(10, 6); STEP(11, 6);
  REDUCE(1, 0);
  STEP(12, 6); STEP(13, 6); STEP(14, 6); STEP(15, 6); STEP(16, 6); STEP(17, 6);
  REDUCE(2, 0);
  STEP(18, 6); STEP(19, 6); STEP(20, 6); STEP(21, 4); STEP(22, 2); STEP(23, 0);
  REDUCE(3, 1);
#undef STEP
#undef REDUCE
#undef GLD_ENC
#undef APK

  if (tid < 192) scomb[tid] = sacc_t;
  __syncthreads();
  if (tid < 64) {
    const int b = tid >> 5, j = tid & 31;
    float tot = scomb[b*32 + j] + scomb[(b + 2)*32 + j] + scomb[(b + 4)*32 + j];
    atomicAdd(&s_out[b*768 + jb*32 + j], tot);
  }
}

// ---------- out = s * seq ----------
__global__ __launch_bounds__(256) void scale_kernel(const float* __restrict__ s,
                                                    const float* __restrict__ seq_in,
                                                    float* __restrict__ seq_out) {
  int idx = blockIdx.x * 256 + threadIdx.x;
  seq_out[idx] = s[idx >> 6] * seq_in[idx];
}

extern "C" void kernel_launch(void* const* d_in, const int* in_sizes, int n_in,
                              void* d_out, int out_size, void* d_ws, size_t ws_size,
                              hipStream_t stream) {
  const float* seq  = (const float*)d_in[0];
  const float* enc  = (const float*)d_in[1];
  const int*   mask = (const int*)d_in[2];
  const float* W11  = (const float*)d_in[3];
  const float* b11  = (const float*)d_in[4];
  const float* W12  = (const float*)d_in[5];
  const float* b12  = (const float*)d_in[6];
  const float* W21  = (const float*)d_in[7];
  const float* b21  = (const float*)d_in[8];
  const float* W22  = (const float*)d_in[9];
  const float* b22  = (const float*)d_in[10];
  float* out = (float*)d_out;

  float* ws = (float*)d_ws;
  size_t off = 0;
  float* mprep = ws + off;                 off += 768*768;
  unsigned* apk2 = (unsigned*)(ws + off);  off += 2*768*160;
  float* zej = ws + off;                   off += 2*768*160;
  unsigned* wpk = (unsigned*)(ws + off);   off += 1280;
  float* w2pad = ws + off;                 off += 160;
  float* sacc1 = ws + off;                 off += 2*768;
  float* sacc2 = ws + off;                 off += 2*768;
  float* seq_mid = ws + off;               off += 2*768*64;
  unsigned* encpk = (unsigned*)(ws + off); off += 768*768*8;

  pre_kernel<<<9984, 256, 0, stream>>>(enc, encpk, mask, mprep);

  // hop 1
  prep_kernel<false><<<96, 256, 0, stream>>>(seq, nullptr, nullptr, W11, b11, W12,
                                             apk2, zej, wpk, w2pad, sacc1);
  edge_kernel<<<dim3(24, 32), 320, 0, stream>>>(encpk, (const uint2*)apk2, zej, wpk,
                                                w2pad, b12, mprep, sacc1);

  // hop 2 (prep fuses the former scale_kernel: seq_mid = sacc1 * seq)
  prep_kernel<true><<<96, 256, 0, stream>>>(seq, sacc1, seq_mid, W21, b21, W22,
                                            apk2, zej, wpk, w2pad, sacc2);
  edge_kernel<<<dim3(24, 32), 320, 0, stream>>>(encpk, (const uint2*)apk2, zej, wpk,
                                                w2pad, b22, mprep, sacc2);
  scale_kernel<<<384, 256, 0, stream>>>(sacc2, seq_mid, out);
}